// Round 7
// baseline (828.405 us; speedup 1.0000x reference)
//
#include <hip/hip_runtime.h>
#include <cmath>

#define BB 8
#define CC 256
#define CQ 64
#define NN 4096
constexpr float INV_N = 1.0f / 4096.0f;

typedef __attribute__((ext_vector_type(8))) short short8;
typedef __attribute__((ext_vector_type(4))) short short4v;
typedef __attribute__((ext_vector_type(4))) float float4v;

__device__ __forceinline__ short f2bf(float f) {
  union { float f; unsigned u; } x; x.f = f;
  unsigned r = x.u + 0x7fffu + ((x.u >> 16) & 1u);
  return (short)(r >> 16);
}

__device__ __forceinline__ short elubf(float s) {
  const float e = (s > 0.f) ? s : (__expf(s) - 1.f);
  return f2bf(e * INV_N);
}

// ---------------------------------------------------------------------------
// prep: blocks 0..63 -> Wv' = Wg@Wv (fp32 accum, bf16 out), 32x32 tiles;
//       block 64 -> convert wq,wk to bf16; block 65 -> bv' = Wg@bv (fp32).
// ---------------------------------------------------------------------------
__global__ __launch_bounds__(256) void prep_kernel(
    const float* __restrict__ wq, const float* __restrict__ wk,
    const float* __restrict__ wv, const float* __restrict__ wg,
    const float* __restrict__ bv,
    short* __restrict__ wqbf, short* __restrict__ wkbf,
    short* __restrict__ wvpbf, float* __restrict__ bvp) {
  const int bx = blockIdx.x;
  const int tid = threadIdx.x;
  if (bx < 64) {
    const int o0 = (bx >> 3) * 32, c0 = (bx & 7) * 32;
    const int cc = tid & 31, oo = tid >> 5;  // oo 0..7
    float acc[4] = {0.f, 0.f, 0.f, 0.f};
    for (int u = 0; u < 256; ++u) {
      const float xv = wv[(size_t)u * 256 + c0 + cc];
#pragma unroll
      for (int i = 0; i < 4; ++i)
        acc[i] += wg[(size_t)(o0 + oo * 4 + i) * 256 + u] * xv;
    }
#pragma unroll
    for (int i = 0; i < 4; ++i)
      wvpbf[(size_t)(o0 + oo * 4 + i) * 256 + c0 + cc] = f2bf(acc[i]);
  } else if (bx == 64) {
#pragma unroll 4
    for (int t = 0; t < 16; ++t) {
      const int idx = (t * 256 + tid) * 4;
      const float4 a = *reinterpret_cast<const float4*>(&wq[idx]);
      short4v p; p.x = f2bf(a.x); p.y = f2bf(a.y); p.z = f2bf(a.z); p.w = f2bf(a.w);
      *reinterpret_cast<short4v*>(&wqbf[idx]) = p;
      const float4 b4 = *reinterpret_cast<const float4*>(&wk[idx]);
      short4v q4; q4.x = f2bf(b4.x); q4.y = f2bf(b4.y); q4.z = f2bf(b4.z); q4.w = f2bf(b4.w);
      *reinterpret_cast<short4v*>(&wkbf[idx]) = q4;
    }
  } else {
    float acc = 0.f;
    for (int u = 0; u < 256; ++u) acc += wg[(size_t)tid * 256 + u] * bv[u];
    bvp[tid] = acc;
  }
}

// ---------------------------------------------------------------------------
// qkv v3: NO LDS, NO barriers. 128-thr blocks (2 waves), grid (B, NN/32).
// Each lane loads its X column-slab (64 scalar fp32, 64B-segment coalesced)
// into registers, converts to bf16 B-frags; 6 chunks of 64 output channels
// (q | k | vtilde0..3) via MFMA with bf16 weights (A-frags) from L2.
// ---------------------------------------------------------------------------
__global__ __launch_bounds__(128)
__attribute__((amdgpu_waves_per_eu(4, 4))) void qkv_kernel(
    const float* __restrict__ X,
    const short* __restrict__ wqbf, const short* __restrict__ wkbf,
    const short* __restrict__ wvpbf,
    const float* __restrict__ bq, const float* __restrict__ bk,
    const float* __restrict__ bvp,
    short* __restrict__ qt, short* __restrict__ kt, short* __restrict__ vt) {
  const int tid = threadIdx.x;
  const int wid = tid >> 6;
  const int lane = tid & 63, quad = lane >> 4, l16 = lane & 15;
  const int b = blockIdx.x;
  const int nb = blockIdx.y * 32 + wid * 16;

  // X column slab: c = s*32 + quad*8 + j, n = nb + l16
  float xv[64];
#pragma unroll
  for (int s = 0; s < 8; ++s)
#pragma unroll
    for (int j = 0; j < 8; ++j)
      xv[s * 8 + j] =
          X[((size_t)b * CC + s * 32 + quad * 8 + j) * NN + nb + l16];

  short8 bx[8];
#pragma unroll
  for (int s = 0; s < 8; ++s)
#pragma unroll
    for (int j = 0; j < 8; ++j) bx[s][j] = f2bf(xv[s * 8 + j]);

  const short* Wsrc[6] = {wqbf, wkbf, wvpbf, wvpbf + 64 * 256,
                          wvpbf + 128 * 256, wvpbf + 192 * 256};

#pragma unroll
  for (int ch = 0; ch < 6; ++ch) {
    const short* W = Wsrc[ch];
    float4v acc[4];
#pragma unroll
    for (int ot = 0; ot < 4; ++ot) acc[ot] = float4v{0.f, 0.f, 0.f, 0.f};

#pragma unroll
    for (int s = 0; s < 8; ++s) {
#pragma unroll
      for (int ot = 0; ot < 4; ++ot) {
        const short8 a = *reinterpret_cast<const short8*>(
            &W[(size_t)(ot * 16 + l16) * CC + s * 32 + quad * 8]);
        acc[ot] =
            __builtin_amdgcn_mfma_f32_16x16x32_bf16(a, bx[s], acc[ot], 0, 0, 0);
      }
    }

    // D: col(n)=l16, row(o)=quad*4+r
    if (ch < 2) {
      const float* bias = (ch == 0) ? bq : bk;
      short* dst = (ch == 0) ? qt : kt;
#pragma unroll
      for (int ot = 0; ot < 4; ++ot) {
        const float4v bv4 =
            *reinterpret_cast<const float4v*>(&bias[ot * 16 + quad * 4]);
        short4v pk;
#pragma unroll
        for (int r = 0; r < 4; ++r) pk[r] = f2bf(acc[ot][r] + bv4[r]);
        *reinterpret_cast<short4v*>(
            &dst[((size_t)b * NN + nb + l16) * 64 + ot * 16 + quad * 4]) = pk;
      }
    } else {
      const int obase = (ch - 2) * 64;
#pragma unroll
      for (int ot = 0; ot < 4; ++ot) {
        const float4v bv4 = *reinterpret_cast<const float4v*>(
            &bvp[obase + ot * 16 + quad * 4]);
#pragma unroll
        for (int r = 0; r < 4; ++r)
          vt[((size_t)b * CC + obase + ot * 16 + quad * 4 + r) * NN + nb +
             l16] = f2bf(acc[ot][r] + bv4[r]);
      }
    }
  }
}

// ---------------------------------------------------------------------------
// attn r7 "wave-autonomous flash": ZERO __syncthreads.
// Wave = 16 m x 128 c. Block = 4 waves = 32 m x 256 c. Grid (B, NN/32) =
// 1024 blocks = 4/CU = 16 waves/CU (VGPR budget 128 via waves_per_eu(4,4)).
// Per 32-n window: wave computes its own S (2 subtiles, K=64), elu -> E
// through a WAVE-PRIVATE LDS slab (lane-flat layout: reads conflict-free,
// writes 2-way=free; intra-wave LDS is ordered -> no barrier), then PV
// (8 c-tiles, K=32). v/q prefetched one window ahead. Double-buffered slab
// gives a full window of write->read cover. Gamma folded into vtilde.
// ---------------------------------------------------------------------------
__global__ __launch_bounds__(256)
__attribute__((amdgpu_waves_per_eu(4, 4))) void attn_kernel(
    const short* __restrict__ qt, const short* __restrict__ kt,
    const short* __restrict__ vt, const float* __restrict__ bg,
    float* __restrict__ out) {
  __shared__ short Es[4][2][512];  // [wave][buf][lane-flat E tile], 8 KB

  const int tid = threadIdx.x;
  const int wid = tid >> 6;
  const int lane = tid & 63, quad = lane >> 4, l16 = lane & 15;
  const int b = blockIdx.x;
  const int M = blockIdx.y * 32 + (wid & 1) * 16;  // wave m-base
  const int c0 = (wid >> 1) * 128;                 // wave c-base

  // k B-frags (resident): B[k=c][col=m=l16]
  const short8 kf0 = *reinterpret_cast<const short8*>(
      &kt[((size_t)b * NN + M + l16) * 64 + quad * 8]);
  const short8 kf1 = *reinterpret_cast<const short8*>(
      &kt[((size_t)b * NN + M + l16) * 64 + 32 + quad * 8]);

  const short* qb = qt + ((size_t)b * NN) * 64 + quad * 8;          // + n*64
  const short* vb = vt + ((size_t)b * CC + c0 + l16) * NN + quad * 8;

  short* es = &Es[wid][0][0];
  // write base: flat dest ((u*2 + quad>>1)*16 + l16)*8 + (quad&1)*4
  const int wbase = (quad >> 1) * 128 + l16 * 8 + (quad & 1) * 4;
  const int rbase = lane * 8;

  float4v acc[8];
#pragma unroll
  for (int i = 0; i < 8; ++i) acc[i] = float4v{0.f, 0.f, 0.f, 0.f};

  // q A-frags for the S being computed next: [u][K-half]
  short8 aq0, aq1, aq2, aq3;
#define LOADQ(t)                                                               \
  {                                                                            \
    const size_t n0 = (size_t)(t) * 32;                                        \
    aq0 = *reinterpret_cast<const short8*>(qb + (n0 + l16) * 64);              \
    aq1 = *reinterpret_cast<const short8*>(qb + (n0 + l16) * 64 + 32);         \
    aq2 = *reinterpret_cast<const short8*>(qb + (n0 + 16 + l16) * 64);         \
    aq3 = *reinterpret_cast<const short8*>(qb + (n0 + 16 + l16) * 64 + 32);    \
  }

#define S_STORE(buf)                                                           \
  {                                                                            \
    float4v s0 = {0.f, 0.f, 0.f, 0.f}, s1 = {0.f, 0.f, 0.f, 0.f};             \
    s0 = __builtin_amdgcn_mfma_f32_16x16x32_bf16(aq0, kf0, s0, 0, 0, 0);       \
    s0 = __builtin_amdgcn_mfma_f32_16x16x32_bf16(aq1, kf1, s0, 0, 0, 0);       \
    s1 = __builtin_amdgcn_mfma_f32_16x16x32_bf16(aq2, kf0, s1, 0, 0, 0);       \
    s1 = __builtin_amdgcn_mfma_f32_16x16x32_bf16(aq3, kf1, s1, 0, 0, 0);       \
    short4v pk0, pk1;                                                          \
    pk0[0] = elubf(s0[0]); pk0[1] = elubf(s0[1]);                              \
    pk0[2] = elubf(s0[2]); pk0[3] = elubf(s0[3]);                              \
    pk1[0] = elubf(s1[0]); pk1[1] = elubf(s1[1]);                              \
    pk1[2] = elubf(s1[2]); pk1[3] = elubf(s1[3]);                              \
    *reinterpret_cast<short4v*>(&es[(buf)*512 + wbase]) = pk0;                 \
    *reinterpret_cast<short4v*>(&es[(buf)*512 + 256 + wbase]) = pk1;           \
  }

  // v A-frags for the current PV window
  short8 av[8];
#pragma unroll
  for (int ct = 0; ct < 8; ++ct)
    av[ct] = *reinterpret_cast<const short8*>(vb + (size_t)ct * 16 * NN);

  LOADQ(0);
  S_STORE(0);   // S(0) -> buf 0
  LOADQ(1);

  for (int t = 0; t < 127; ++t) {
    const int rb = t & 1, wb = rb ^ 1;
    const short8 breg = *reinterpret_cast<const short8*>(&es[rb * 512 + rbase]);
    // S(t+1) -> other buffer (no barrier: wave-private, in-order LDS)
    S_STORE(wb);
    // PV(t), then reload av for window t+1
#pragma unroll
    for (int ct = 0; ct < 8; ++ct) {
      acc[ct] =
          __builtin_amdgcn_mfma_f32_16x16x32_bf16(av[ct], breg, acc[ct], 0, 0, 0);
      av[ct] = *reinterpret_cast<const short8*>(
          vb + (size_t)ct * 16 * NN + (size_t)(t + 1) * 32);
    }
    LOADQ(t + 2);  // t=126 -> q(128): over-read lands in kt (allocated)
  }
  // final window t = 127
  {
    const short8 breg = *reinterpret_cast<const short8*>(&es[512 + rbase]);
#pragma unroll
    for (int ct = 0; ct < 8; ++ct)
      acc[ct] =
          __builtin_amdgcn_mfma_f32_16x16x32_bf16(av[ct], breg, acc[ct], 0, 0, 0);
  }

  // epilogue: + bg (gamma folded into vtilde by prep)
#pragma unroll
  for (int ct = 0; ct < 8; ++ct) {
    const float4v bg4 =
        *reinterpret_cast<const float4v*>(&bg[c0 + ct * 16 + quad * 4]);
#pragma unroll
    for (int r = 0; r < 4; ++r) {
      out[((size_t)b * CC + c0 + ct * 16 + quad * 4 + r) * NN + M + l16] =
          acc[ct][r] + bg4[r];
    }
  }
#undef LOADQ
#undef S_STORE
}

// ---------------------------------------------------------------------------
extern "C" void kernel_launch(void* const* d_in, const int* in_sizes, int n_in,
                              void* d_out, int out_size, void* d_ws,
                              size_t ws_size, hipStream_t stream) {
  const float* x  = (const float*)d_in[0];
  const float* wq = (const float*)d_in[1];
  const float* bq = (const float*)d_in[2];
  const float* wk = (const float*)d_in[3];
  const float* bk = (const float*)d_in[4];
  const float* wv = (const float*)d_in[5];
  const float* bv = (const float*)d_in[6];
  const float* wg = (const float*)d_in[7];
  const float* bg = (const float*)d_in[8];
  float* out = (float*)d_out;

  short* qt    = (short*)d_ws;                       // [B][N][64]   4 MB
  short* kt    = qt + (size_t)BB * NN * CQ;          // [B][N][64]   4 MB
  short* vt    = kt + (size_t)BB * NN * CQ;          // [B][C][N]   16 MB
  short* wqbf  = vt + (size_t)BB * CC * NN;          // 32 KB
  short* wkbf  = wqbf + (size_t)CQ * CC;             // 32 KB
  short* wvpbf = wkbf + (size_t)CQ * CC;             // 128 KB
  float* bvp   = (float*)(wvpbf + (size_t)CC * CC);  // 1 KB

  prep_kernel<<<dim3(66), 256, 0, stream>>>(wq, wk, wv, wg, bv,
                                            wqbf, wkbf, wvpbf, bvp);
  qkv_kernel<<<dim3(BB, NN / 32), 128, 0, stream>>>(
      x, wqbf, wkbf, wvpbf, bq, bk, bvp, qt, kt, vt);
  attn_kernel<<<dim3(BB, NN / 32), 256, 0, stream>>>(qt, kt, vt, bg, out);
}